// Round 3
// baseline (718.891 us; speedup 1.0000x reference)
//
#include <hip/hip_runtime.h>

namespace {
constexpr int IMG_H = 376;
constexpr int IMG_W = 1248;
constexpr int HW = IMG_H * IMG_W;
constexpr int CV = 16;
constexpr int CR = 32;
constexpr int CO = CV + CR;   // 48
constexpr int K3 = 27;
constexpr int BLOCK = 256;
constexpr int ROWS = 256;     // rows per block (one per thread in phase 1)
}

// Per-batch precompute: Md = rect[s] @ Trv2c[s]; copy P2[s], prd[s].
// Layout per b (32 floats): [0:16) Md, [16:28) P2, [28] prd_u, [29] prd_v
__global__ void prep_kernel(const float* __restrict__ P2,
                            const float* __restrict__ Trv2c,
                            const float* __restrict__ rect,
                            const float* __restrict__ prd,
                            const int* __restrict__ dummy,
                            float* __restrict__ mats, int B) {
    int b = threadIdx.x;
    if (b >= B) return;
    int s = dummy[b];
    float* o = mats + b * 32;
    const float* R = rect + s * 16;
    const float* T = Trv2c + s * 16;
    for (int i = 0; i < 4; ++i) {
        for (int j = 0; j < 4; ++j) {
            float acc = R[i * 4 + 0] * T[0 * 4 + j];
            acc += R[i * 4 + 1] * T[1 * 4 + j];
            acc += R[i * 4 + 2] * T[2 * 4 + j];
            acc += R[i * 4 + 3] * T[3 * 4 + j];
            o[i * 4 + j] = acc;
        }
    }
    for (int i = 0; i < 12; ++i) o[16 + i] = P2[s * 12 + i];
    o[28] = prd[s * 2 + 0];
    o[29] = prd[s * 2 + 1];
}

__global__ __launch_bounds__(BLOCK) void fuse_kernel(
        const float* __restrict__ vfeat,
        const float* __restrict__ rgb,
        const float* __restrict__ mats,
        const int* __restrict__ vcoords,
        float* __restrict__ out,
        int N) {
    const int M = N * K3;

    __shared__ float sw0[ROWS], sw1[ROWS], sw2[ROWS], sw3[ROWS];
    __shared__ int   so0[ROWS], so1[ROWS], so2[ROWS], so3[ROWS];
    __shared__ int   sn[ROWS];
    __shared__ int   sbo[ROWS];   // b * CR * HW (element offset into rgb)
    __shared__ int   sv[ROWS];    // valid flag

    const int t = threadIdx.x;
    const int rowBase = blockIdx.x * ROWS;

    // ---------- phase 1: geometry for ROWS rows, one per thread ----------
    {
        int m = rowBase + t;
        float w00 = 0.f, w10 = 0.f, w01 = 0.f, w11 = 0.f;
        int o00 = 0, o10 = 0, o01 = 0, o11 = 0;
        int n = 0, bo = 0, valid = 0;
        if (m < M) {
            n = m / K3;
            int kk = m - n * K3;
            int4 vc = ((const int4*)vcoords)[n];
            int b = vc.x;
            int dz = kk / 9;
            int rem = kk - dz * 9;
            int dy = rem / 3;
            int dx = rem - dy * 3;

            float fz = ((float)(vc.y + dz - 1) + 0.5f) * 0.1f - 3.0f;
            float fy = ((float)(vc.z + dy - 1) + 0.5f) * 0.05f - 40.0f;
            float fx = ((float)(vc.w + dx - 1) + 0.5f) * 0.05f;

            const float* Mb = mats + b * 32;
            float cam0 = Mb[0]  * fx + Mb[1]  * fy + Mb[2]  * fz + Mb[3];
            float cam1 = Mb[4]  * fx + Mb[5]  * fy + Mb[6]  * fz + Mb[7];
            float cam2 = Mb[8]  * fx + Mb[9]  * fy + Mb[10] * fz + Mb[11];
            float cam3 = Mb[12] * fx + Mb[13] * fy + Mb[14] * fz + Mb[15];

            float img0 = Mb[16] * cam0 + Mb[17] * cam1 + Mb[18] * cam2 + Mb[19] * cam3;
            float img1 = Mb[20] * cam0 + Mb[21] * cam1 + Mb[22] * cam2 + Mb[23] * cam3;
            float img2 = Mb[24] * cam0 + Mb[25] * cam1 + Mb[26] * cam2 + Mb[27] * cam3;

            float depth = img2;
            float d = fmaxf(depth, 0.001f);
            float u = img0 / d + Mb[28];
            float v = img1 / d + Mb[29];

            valid = (depth > 0.001f) && (u >= 0.0f) && (u <= (float)(IMG_W - 1))
                    && (v >= 0.0f) && (v <= (float)(IMG_H - 1));

            if (valid) {
                float uc = fminf(fmaxf(u, 0.0f), (float)(IMG_W - 1));
                float vcl = fminf(fmaxf(v, 0.0f), (float)(IMG_H - 1));
                int x0 = (int)floorf(uc);
                int y0 = (int)floorf(vcl);
                int x1 = min(x0 + 1, IMG_W - 1);
                int y1 = min(y0 + 1, IMG_H - 1);
                float wx = uc - (float)x0;
                float wy = vcl - (float)y0;
                w00 = (1.0f - wx) * (1.0f - wy);
                w10 = wx * (1.0f - wy);
                w01 = (1.0f - wx) * wy;
                w11 = wx * wy;
                o00 = y0 * IMG_W + x0;
                o10 = y0 * IMG_W + x1;
                o01 = y1 * IMG_W + x0;
                o11 = y1 * IMG_W + x1;
                bo = b * (CR * HW);
            }
        }
        sw0[t] = w00; sw1[t] = w10; sw2[t] = w01; sw3[t] = w11;
        so0[t] = o00; so1[t] = o10; so2[t] = o01; so3[t] = o11;
        sn[t] = n; sbo[t] = bo; sv[t] = valid;
    }

    __syncthreads();

    // ---------- phase 2: each wave emits 64 rows, lane c -> channel c ----------
    const int wave = t >> 6;      // 0..3
    const int c = t & 63;         // channel (0..47 active)
    const int rEnd = min(ROWS, M - rowBase);
    const int r0 = wave * (ROWS / 4);
    const int r1 = min(r0 + (ROWS / 4), rEnd);

    for (int r = r0; r < r1; ++r) {
        int m = rowBase + r;
        float val = 0.0f;
        if (c < CV) {
            val = vfeat[(size_t)sn[r] * CV + c];
        } else if (c < CO) {
            if (sv[r]) {
                const float* p = rgb + (size_t)sbo[r] + (size_t)(c - CV) * HW;
                val = p[so0[r]] * sw0[r] + p[so1[r]] * sw1[r]
                    + p[so2[r]] * sw2[r] + p[so3[r]] * sw3[r];
            }
        }
        if (c < CO) {
            out[(size_t)m * CO + c] = val;
        }
    }
}

extern "C" void kernel_launch(void* const* d_in, const int* in_sizes, int n_in,
                              void* d_out, int out_size, void* d_ws, size_t ws_size,
                              hipStream_t stream) {
    const float* vfeat  = (const float*)d_in[0];
    const float* rgb    = (const float*)d_in[1];
    const float* P2     = (const float*)d_in[2];
    const float* Trv2c  = (const float*)d_in[3];
    const float* rect   = (const float*)d_in[4];
    const float* prd    = (const float*)d_in[5];
    const int* vcoords  = (const int*)d_in[6];
    const int* dummy    = (const int*)d_in[7];
    float* out = (float*)d_out;

    int B = in_sizes[7];
    int N = in_sizes[6] / 4;
    float* mats = (float*)d_ws;   // B * 32 floats

    prep_kernel<<<1, 64, 0, stream>>>(P2, Trv2c, rect, prd, dummy, mats, B);

    int M = N * K3;
    int blocks = (M + ROWS - 1) / ROWS;
    fuse_kernel<<<blocks, BLOCK, 0, stream>>>(vfeat, rgb, mats, vcoords, out, N);
}

// Round 4
// 141.620 us; speedup vs baseline: 5.0762x; 5.0762x over previous
//
#include <hip/hip_runtime.h>

namespace {
constexpr int IMG_H = 376;
constexpr int IMG_W = 1248;
constexpr int HW = IMG_H * IMG_W;
constexpr int CV = 16;
constexpr int CR = 32;
constexpr int CO = CV + CR;   // 48
constexpr int K3 = 27;
constexpr int BLOCK = 256;    // 4 waves; each wave owns 64 rows
constexpr int LDSPAD = CO + 1; // 49 -> (row*49+c)%32 = (row*17+c)%32, conflict-free
}

// Per-batch precompute: Md = rect[s] @ Trv2c[s]; copy P2[s], prd[s].
// Layout per b (32 floats): [0:16) Md, [16:28) P2, [28] prd_u, [29] prd_v
__global__ void prep_kernel(const float* __restrict__ P2,
                            const float* __restrict__ Trv2c,
                            const float* __restrict__ rect,
                            const float* __restrict__ prd,
                            const int* __restrict__ dummy,
                            float* __restrict__ mats, int B) {
    int b = threadIdx.x;
    if (b >= B) return;
    int s = dummy[b];
    float* o = mats + b * 32;
    const float* R = rect + s * 16;
    const float* T = Trv2c + s * 16;
    for (int i = 0; i < 4; ++i) {
        for (int j = 0; j < 4; ++j) {
            float acc = R[i * 4 + 0] * T[0 * 4 + j];
            acc += R[i * 4 + 1] * T[1 * 4 + j];
            acc += R[i * 4 + 2] * T[2 * 4 + j];
            acc += R[i * 4 + 3] * T[3 * 4 + j];
            o[i * 4 + j] = acc;
        }
    }
    for (int i = 0; i < 12; ++i) o[16 + i] = P2[s * 12 + i];
    o[28] = prd[s * 2 + 0];
    o[29] = prd[s * 2 + 1];
}

__global__ __launch_bounds__(BLOCK) void fuse_kernel(
        const float* __restrict__ vfeat,
        const float* __restrict__ rgb,
        const float* __restrict__ mats,
        const int* __restrict__ vcoords,
        float* __restrict__ out,
        int N) {
    const int M = N * K3;
    __shared__ float lds[4][16][LDSPAD];   // 12.5 KB total

    const int t = threadIdx.x;
    const int wave = t >> 6;
    const int lane = t & 63;
    const int waveBase = blockIdx.x * BLOCK + wave * 64;
    const int m = waveBase + lane;
    const bool inR = (m < M);

    // ---------- phase 1: thread-per-row geometry + gather into registers ----------
    float s[CO];
    #pragma unroll
    for (int c = 0; c < CO; ++c) s[c] = 0.0f;

    if (inR) {
        int n = m / K3;
        int kk = m - n * K3;
        int4 vc = ((const int4*)vcoords)[n];
        int b = vc.x;
        int dz = kk / 9;
        int rem = kk - dz * 9;
        int dy = rem / 3;
        int dx = rem - dy * 3;

        float fz = ((float)(vc.y + dz - 1) + 0.5f) * 0.1f - 3.0f;
        float fy = ((float)(vc.z + dy - 1) + 0.5f) * 0.05f - 40.0f;
        float fx = ((float)(vc.w + dx - 1) + 0.5f) * 0.05f;

        const float* Mb = mats + b * 32;
        float cam0 = Mb[0]  * fx + Mb[1]  * fy + Mb[2]  * fz + Mb[3];
        float cam1 = Mb[4]  * fx + Mb[5]  * fy + Mb[6]  * fz + Mb[7];
        float cam2 = Mb[8]  * fx + Mb[9]  * fy + Mb[10] * fz + Mb[11];
        float cam3 = Mb[12] * fx + Mb[13] * fy + Mb[14] * fz + Mb[15];

        float img0 = Mb[16] * cam0 + Mb[17] * cam1 + Mb[18] * cam2 + Mb[19] * cam3;
        float img1 = Mb[20] * cam0 + Mb[21] * cam1 + Mb[22] * cam2 + Mb[23] * cam3;
        float img2 = Mb[24] * cam0 + Mb[25] * cam1 + Mb[26] * cam2 + Mb[27] * cam3;

        float depth = img2;
        float d = fmaxf(depth, 0.001f);
        float u = img0 / d + Mb[28];
        float v = img1 / d + Mb[29];

        bool valid = (depth > 0.001f) && (u >= 0.0f) && (u <= (float)(IMG_W - 1))
                     && (v >= 0.0f) && (v <= (float)(IMG_H - 1));

        // voxel features (scalar assigns keep s[] in registers)
        const float4* vp4 = (const float4*)(vfeat + (size_t)n * CV);
        float4 vf0 = vp4[0], vf1 = vp4[1], vf2 = vp4[2], vf3 = vp4[3];
        s[0] = vf0.x;  s[1] = vf0.y;  s[2]  = vf0.z;  s[3]  = vf0.w;
        s[4] = vf1.x;  s[5] = vf1.y;  s[6]  = vf1.z;  s[7]  = vf1.w;
        s[8] = vf2.x;  s[9] = vf2.y;  s[10] = vf2.z;  s[11] = vf2.w;
        s[12] = vf3.x; s[13] = vf3.y; s[14] = vf3.z;  s[15] = vf3.w;

        if (valid) {
            float uc = fminf(fmaxf(u, 0.0f), (float)(IMG_W - 1));
            float vcl = fminf(fmaxf(v, 0.0f), (float)(IMG_H - 1));
            int x0 = (int)floorf(uc);
            int y0 = (int)floorf(vcl);
            int x1 = min(x0 + 1, IMG_W - 1);
            int y1 = min(y0 + 1, IMG_H - 1);
            float wx = uc - (float)x0;
            float wy = vcl - (float)y0;
            float w00 = (1.0f - wx) * (1.0f - wy);
            float w10 = wx * (1.0f - wy);
            float w01 = (1.0f - wx) * wy;
            float w11 = wx * wy;
            const float* base = rgb + (size_t)b * CR * HW;
            int o00 = y0 * IMG_W + x0;
            int o10 = y0 * IMG_W + x1;
            int o01 = y1 * IMG_W + x0;
            int o11 = y1 * IMG_W + x1;
            #pragma unroll
            for (int c = 0; c < CR; ++c) {
                const float* p = base + (size_t)c * HW;
                s[CV + c] = p[o00] * w00 + p[o10] * w10
                          + p[o01] * w01 + p[o11] * w11;
            }
        }
    }

    // ---------- phase 2: 4 chunks of 16 rows; reg -> LDS -> coalesced stores ----------
    const size_t total = (size_t)M * CO;
    #pragma unroll 1
    for (int j = 0; j < 4; ++j) {
        __builtin_amdgcn_wave_barrier();
        if ((lane >> 4) == j && inR) {
            int r = lane & 15;
            #pragma unroll
            for (int c = 0; c < CO; ++c) lds[wave][r][c] = s[c];
        }
        __builtin_amdgcn_wave_barrier();
        // chunk output region: rows [waveBase + 16j, +16) -> 768 floats contiguous
        size_t chunkBase = ((size_t)waveBase + (size_t)j * 16) * CO;
        #pragma unroll
        for (int i = 0; i < 3; ++i) {
            int g = i * 64 + lane;            // float4 index within chunk, 0..191
            int row = g / 12;                 // 16 rows * 12 float4s each
            int c4 = (g - row * 12) * 4;
            float4 val = make_float4(lds[wave][row][c4 + 0],
                                     lds[wave][row][c4 + 1],
                                     lds[wave][row][c4 + 2],
                                     lds[wave][row][c4 + 3]);
            size_t idx = chunkBase + (size_t)g * 4;
            if (idx < total) {
                *(float4*)(out + idx) = val;  // 64 lanes x 16B contiguous = 1024B/instr
            }
        }
        __builtin_amdgcn_wave_barrier();
    }
}

extern "C" void kernel_launch(void* const* d_in, const int* in_sizes, int n_in,
                              void* d_out, int out_size, void* d_ws, size_t ws_size,
                              hipStream_t stream) {
    const float* vfeat  = (const float*)d_in[0];
    const float* rgb    = (const float*)d_in[1];
    const float* P2     = (const float*)d_in[2];
    const float* Trv2c  = (const float*)d_in[3];
    const float* rect   = (const float*)d_in[4];
    const float* prd    = (const float*)d_in[5];
    const int* vcoords  = (const int*)d_in[6];
    const int* dummy    = (const int*)d_in[7];
    float* out = (float*)d_out;

    int B = in_sizes[7];
    int N = in_sizes[6] / 4;
    float* mats = (float*)d_ws;   // B * 32 floats

    prep_kernel<<<1, 64, 0, stream>>>(P2, Trv2c, rect, prd, dummy, mats, B);

    int M = N * K3;
    int blocks = (M + BLOCK - 1) / BLOCK;
    fuse_kernel<<<blocks, BLOCK, 0, stream>>>(vfeat, rgb, mats, vcoords, out, N);
}

// Round 6
// 136.484 us; speedup vs baseline: 5.2672x; 1.0376x over previous
//
#include <hip/hip_runtime.h>

namespace {
constexpr int IMG_H = 376;
constexpr int IMG_W = 1248;
constexpr int HW = IMG_H * IMG_W;
constexpr int CV = 16;
constexpr int CR = 32;
constexpr int CO = CV + CR;   // 48
constexpr int K3 = 27;
constexpr int BLOCK = 256;    // 4 waves; each wave owns 64 rows
constexpr int LDSPAD = CO + 1; // 49 -> (row*49+c)%32 = (row*17+c)%32, conflict-free
typedef float floatx4 __attribute__((ext_vector_type(4)));
}

// Per-batch precompute: Md = rect[s] @ Trv2c[s]; copy P2[s], prd[s].
// Layout per b (32 floats): [0:16) Md, [16:28) P2, [28] prd_u, [29] prd_v
__global__ void prep_kernel(const float* __restrict__ P2,
                            const float* __restrict__ Trv2c,
                            const float* __restrict__ rect,
                            const float* __restrict__ prd,
                            const int* __restrict__ dummy,
                            float* __restrict__ mats, int B) {
    int b = threadIdx.x;
    if (b >= B) return;
    int s = dummy[b];
    float* o = mats + b * 32;
    const float* R = rect + s * 16;
    const float* T = Trv2c + s * 16;
    for (int i = 0; i < 4; ++i) {
        for (int j = 0; j < 4; ++j) {
            float acc = R[i * 4 + 0] * T[0 * 4 + j];
            acc += R[i * 4 + 1] * T[1 * 4 + j];
            acc += R[i * 4 + 2] * T[2 * 4 + j];
            acc += R[i * 4 + 3] * T[3 * 4 + j];
            o[i * 4 + j] = acc;
        }
    }
    for (int i = 0; i < 12; ++i) o[16 + i] = P2[s * 12 + i];
    o[28] = prd[s * 2 + 0];
    o[29] = prd[s * 2 + 1];
}

__global__ __launch_bounds__(BLOCK) void fuse_kernel(
        const float* __restrict__ vfeat,
        const float* __restrict__ rgb,
        const float* __restrict__ mats,
        const int* __restrict__ vcoords,
        float* __restrict__ out,
        int N) {
    const int M = N * K3;
    __shared__ float lds[4][16][LDSPAD];   // 12.5 KB total

    const int t = threadIdx.x;
    const int wave = t >> 6;
    const int lane = t & 63;
    const int waveBase = blockIdx.x * BLOCK + wave * 64;
    const int m = waveBase + lane;
    const bool inR = (m < M);

    // ---------- phase 1: thread-per-row geometry + gather into registers ----------
    float s[CO];
    #pragma unroll
    for (int c = 0; c < CO; ++c) s[c] = 0.0f;

    if (inR) {
        int n = m / K3;
        int kk = m - n * K3;
        int4 vc = ((const int4*)vcoords)[n];
        int b = vc.x;
        int dz = kk / 9;
        int rem = kk - dz * 9;
        int dy = rem / 3;
        int dx = rem - dy * 3;

        float fz = ((float)(vc.y + dz - 1) + 0.5f) * 0.1f - 3.0f;
        float fy = ((float)(vc.z + dy - 1) + 0.5f) * 0.05f - 40.0f;
        float fx = ((float)(vc.w + dx - 1) + 0.5f) * 0.05f;

        const float* Mb = mats + b * 32;
        float cam0 = Mb[0]  * fx + Mb[1]  * fy + Mb[2]  * fz + Mb[3];
        float cam1 = Mb[4]  * fx + Mb[5]  * fy + Mb[6]  * fz + Mb[7];
        float cam2 = Mb[8]  * fx + Mb[9]  * fy + Mb[10] * fz + Mb[11];
        float cam3 = Mb[12] * fx + Mb[13] * fy + Mb[14] * fz + Mb[15];

        float img0 = Mb[16] * cam0 + Mb[17] * cam1 + Mb[18] * cam2 + Mb[19] * cam3;
        float img1 = Mb[20] * cam0 + Mb[21] * cam1 + Mb[22] * cam2 + Mb[23] * cam3;
        float img2 = Mb[24] * cam0 + Mb[25] * cam1 + Mb[26] * cam2 + Mb[27] * cam3;

        float depth = img2;
        float d = fmaxf(depth, 0.001f);
        float u = img0 / d + Mb[28];
        float v = img1 / d + Mb[29];

        bool valid = (depth > 0.001f) && (u >= 0.0f) && (u <= (float)(IMG_W - 1))
                     && (v >= 0.0f) && (v <= (float)(IMG_H - 1));

        // voxel features (scalar assigns keep s[] in registers)
        const float4* vp4 = (const float4*)(vfeat + (size_t)n * CV);
        float4 vf0 = vp4[0], vf1 = vp4[1], vf2 = vp4[2], vf3 = vp4[3];
        s[0] = vf0.x;  s[1] = vf0.y;  s[2]  = vf0.z;  s[3]  = vf0.w;
        s[4] = vf1.x;  s[5] = vf1.y;  s[6]  = vf1.z;  s[7]  = vf1.w;
        s[8] = vf2.x;  s[9] = vf2.y;  s[10] = vf2.z;  s[11] = vf2.w;
        s[12] = vf3.x; s[13] = vf3.y; s[14] = vf3.z;  s[15] = vf3.w;

        if (valid) {
            float uc = fminf(fmaxf(u, 0.0f), (float)(IMG_W - 1));
            float vcl = fminf(fmaxf(v, 0.0f), (float)(IMG_H - 1));
            int x0 = (int)floorf(uc);
            int y0 = (int)floorf(vcl);
            int x1 = min(x0 + 1, IMG_W - 1);
            int y1 = min(y0 + 1, IMG_H - 1);
            float wx = uc - (float)x0;
            float wy = vcl - (float)y0;
            float w00 = (1.0f - wx) * (1.0f - wy);
            float w10 = wx * (1.0f - wy);
            float w01 = (1.0f - wx) * wy;
            float w11 = wx * wy;
            const float* base = rgb + (size_t)b * CR * HW;
            int o00 = y0 * IMG_W + x0;
            int o10 = y0 * IMG_W + x1;
            int o01 = y1 * IMG_W + x0;
            int o11 = y1 * IMG_W + x1;
            // 4 batches of 8 channels: 32 loads issued per clause before any FMA
            #pragma unroll
            for (int g = 0; g < 4; ++g) {
                float t00[8], t10[8], t01[8], t11[8];
                #pragma unroll
                for (int c = 0; c < 8; ++c) {
                    const float* p = base + (size_t)(g * 8 + c) * HW;
                    t00[c] = p[o00];
                    t10[c] = p[o10];
                    t01[c] = p[o01];
                    t11[c] = p[o11];
                }
                #pragma unroll
                for (int c = 0; c < 8; ++c) {
                    s[CV + g * 8 + c] = t00[c] * w00 + t10[c] * w10
                                      + t01[c] * w01 + t11[c] * w11;
                }
            }
        }
    }

    // ---------- phase 2: 4 chunks of 16 rows; reg -> LDS -> coalesced stores ----------
    const size_t total = (size_t)M * CO;
    #pragma unroll 1
    for (int j = 0; j < 4; ++j) {
        __builtin_amdgcn_wave_barrier();
        if ((lane >> 4) == j && inR) {
            int r = lane & 15;
            #pragma unroll
            for (int c = 0; c < CO; ++c) lds[wave][r][c] = s[c];
        }
        __builtin_amdgcn_wave_barrier();
        // chunk output region: rows [waveBase + 16j, +16) -> 768 floats contiguous
        size_t chunkBase = ((size_t)waveBase + (size_t)j * 16) * CO;
        #pragma unroll
        for (int i = 0; i < 3; ++i) {
            int g = i * 64 + lane;            // float4 index within chunk, 0..191
            int row = g / 12;                 // 16 rows * 12 float4s each
            int c4 = (g - row * 12) * 4;
            floatx4 val;
            val.x = lds[wave][row][c4 + 0];
            val.y = lds[wave][row][c4 + 1];
            val.z = lds[wave][row][c4 + 2];
            val.w = lds[wave][row][c4 + 3];
            size_t idx = chunkBase + (size_t)g * 4;
            if (idx < total) {
                // non-temporal: keep the 202 MB write stream from evicting rgb in L2
                __builtin_nontemporal_store(val, (floatx4*)(out + idx));
            }
        }
        __builtin_amdgcn_wave_barrier();
    }
}

extern "C" void kernel_launch(void* const* d_in, const int* in_sizes, int n_in,
                              void* d_out, int out_size, void* d_ws, size_t ws_size,
                              hipStream_t stream) {
    const float* vfeat  = (const float*)d_in[0];
    const float* rgb    = (const float*)d_in[1];
    const float* P2     = (const float*)d_in[2];
    const float* Trv2c  = (const float*)d_in[3];
    const float* rect   = (const float*)d_in[4];
    const float* prd    = (const float*)d_in[5];
    const int* vcoords  = (const int*)d_in[6];
    const int* dummy    = (const int*)d_in[7];
    float* out = (float*)d_out;

    int B = in_sizes[7];
    int N = in_sizes[6] / 4;
    float* mats = (float*)d_ws;   // B * 32 floats

    prep_kernel<<<1, 64, 0, stream>>>(P2, Trv2c, rect, prd, dummy, mats, B);

    int M = N * K3;
    int blocks = (M + BLOCK - 1) / BLOCK;
    fuse_kernel<<<blocks, BLOCK, 0, stream>>>(vfeat, rgb, mats, vcoords, out, N);
}

// Round 7
// 134.058 us; speedup vs baseline: 5.3625x; 1.0181x over previous
//
#include <hip/hip_runtime.h>

namespace {
constexpr int IMG_H = 376;
constexpr int IMG_W = 1248;
constexpr int HW = IMG_H * IMG_W;
constexpr int CV = 16;
constexpr int CR = 32;
constexpr int CO = CV + CR;   // 48
constexpr int K3 = 27;
constexpr int BLOCK = 256;    // 4 waves; each wave owns 64 rows
constexpr int LDSPAD = CO + 1; // 49 -> (row*49+c)%32 = (row*17+c)%32, conflict-free
typedef float floatx4 __attribute__((ext_vector_type(4)));
typedef float floatx2 __attribute__((ext_vector_type(2)));
typedef floatx2 __attribute__((aligned(4))) floatx2u;   // dword-aligned 8B loads
}

// Per-batch precompute: Md = rect[s] @ Trv2c[s]; copy P2[s], prd[s].
// Layout per b (32 floats): [0:16) Md, [16:28) P2, [28] prd_u, [29] prd_v
__global__ void prep_kernel(const float* __restrict__ P2,
                            const float* __restrict__ Trv2c,
                            const float* __restrict__ rect,
                            const float* __restrict__ prd,
                            const int* __restrict__ dummy,
                            float* __restrict__ mats, int B) {
    int b = threadIdx.x;
    if (b >= B) return;
    int s = dummy[b];
    float* o = mats + b * 32;
    const float* R = rect + s * 16;
    const float* T = Trv2c + s * 16;
    for (int i = 0; i < 4; ++i) {
        for (int j = 0; j < 4; ++j) {
            float acc = R[i * 4 + 0] * T[0 * 4 + j];
            acc += R[i * 4 + 1] * T[1 * 4 + j];
            acc += R[i * 4 + 2] * T[2 * 4 + j];
            acc += R[i * 4 + 3] * T[3 * 4 + j];
            o[i * 4 + j] = acc;
        }
    }
    for (int i = 0; i < 12; ++i) o[16 + i] = P2[s * 12 + i];
    o[28] = prd[s * 2 + 0];
    o[29] = prd[s * 2 + 1];
}

__global__ __launch_bounds__(BLOCK) void fuse_kernel(
        const float* __restrict__ vfeat,
        const float* __restrict__ rgb,
        const float* __restrict__ mats,
        const int* __restrict__ vcoords,
        float* __restrict__ out,
        int N) {
    const int M = N * K3;
    __shared__ float lds[4][16][LDSPAD];   // 12.5 KB total

    const int t = threadIdx.x;
    const int wave = t >> 6;
    const int lane = t & 63;
    const int waveBase = blockIdx.x * BLOCK + wave * 64;
    const int m = waveBase + lane;
    const bool inR = (m < M);

    // ---------- phase 1: thread-per-row geometry + gather into registers ----------
    float s[CO];
    #pragma unroll
    for (int c = 0; c < CO; ++c) s[c] = 0.0f;

    if (inR) {
        int n = m / K3;
        int kk = m - n * K3;
        int4 vc = ((const int4*)vcoords)[n];
        int b = vc.x;
        int dz = kk / 9;
        int rem = kk - dz * 9;
        int dy = rem / 3;
        int dx = rem - dy * 3;

        float fz = ((float)(vc.y + dz - 1) + 0.5f) * 0.1f - 3.0f;
        float fy = ((float)(vc.z + dy - 1) + 0.5f) * 0.05f - 40.0f;
        float fx = ((float)(vc.w + dx - 1) + 0.5f) * 0.05f;

        const float* Mb = mats + b * 32;
        float cam0 = Mb[0]  * fx + Mb[1]  * fy + Mb[2]  * fz + Mb[3];
        float cam1 = Mb[4]  * fx + Mb[5]  * fy + Mb[6]  * fz + Mb[7];
        float cam2 = Mb[8]  * fx + Mb[9]  * fy + Mb[10] * fz + Mb[11];
        float cam3 = Mb[12] * fx + Mb[13] * fy + Mb[14] * fz + Mb[15];

        float img0 = Mb[16] * cam0 + Mb[17] * cam1 + Mb[18] * cam2 + Mb[19] * cam3;
        float img1 = Mb[20] * cam0 + Mb[21] * cam1 + Mb[22] * cam2 + Mb[23] * cam3;
        float img2 = Mb[24] * cam0 + Mb[25] * cam1 + Mb[26] * cam2 + Mb[27] * cam3;

        float depth = img2;
        float d = fmaxf(depth, 0.001f);
        float u = img0 / d + Mb[28];
        float v = img1 / d + Mb[29];

        bool valid = (depth > 0.001f) && (u >= 0.0f) && (u <= (float)(IMG_W - 1))
                     && (v >= 0.0f) && (v <= (float)(IMG_H - 1));

        // voxel features (scalar assigns keep s[] in registers)
        const float4* vp4 = (const float4*)(vfeat + (size_t)n * CV);
        float4 vf0 = vp4[0], vf1 = vp4[1], vf2 = vp4[2], vf3 = vp4[3];
        s[0] = vf0.x;  s[1] = vf0.y;  s[2]  = vf0.z;  s[3]  = vf0.w;
        s[4] = vf1.x;  s[5] = vf1.y;  s[6]  = vf1.z;  s[7]  = vf1.w;
        s[8] = vf2.x;  s[9] = vf2.y;  s[10] = vf2.z;  s[11] = vf2.w;
        s[12] = vf3.x; s[13] = vf3.y; s[14] = vf3.z;  s[15] = vf3.w;

        if (valid) {
            // shift-clamp: identical math, guarantees x1=x0+1, y1=y0+1 in-bounds.
            // (at u==W-1: x0=W-2, wx=1 -> all weight on the W-1 tap == reference)
            int x0 = min((int)floorf(u), IMG_W - 2);
            int y0 = min((int)floorf(v), IMG_H - 2);
            float wx = u - (float)x0;
            float wy = v - (float)y0;
            float w00 = (1.0f - wx) * (1.0f - wy);
            float w10 = wx * (1.0f - wy);
            float w01 = (1.0f - wx) * wy;
            float w11 = wx * wy;
            const float* tap = rgb + (size_t)b * CR * HW + (size_t)y0 * IMG_W + x0;
            // 4 batches of 8 channels; per channel: 2x 8B paired-tap loads.
            #pragma unroll
            for (int g = 0; g < 4; ++g) {
                floatx2 r0[8], r1[8];
                #pragma unroll
                for (int c = 0; c < 8; ++c) {
                    const float* p = tap + (size_t)(g * 8 + c) * HW;
                    r0[c] = *(const floatx2u*)p;            // (y0,x0),(y0,x1)
                    r1[c] = *(const floatx2u*)(p + IMG_W);  // (y1,x0),(y1,x1)
                }
                // force the 16 loads of this batch into one clause
                __builtin_amdgcn_sched_group_barrier(0x020, 16, 0); // VMEM_READ x16
                #pragma unroll
                for (int c = 0; c < 8; ++c) {
                    s[CV + g * 8 + c] = r0[c].x * w00 + r0[c].y * w10
                                      + r1[c].x * w01 + r1[c].y * w11;
                }
                __builtin_amdgcn_sched_group_barrier(0x002, 32, 0); // VALU x32
            }
        }
    }

    // ---------- phase 2: 4 chunks of 16 rows; reg -> LDS -> coalesced stores ----------
    const size_t total = (size_t)M * CO;
    #pragma unroll 1
    for (int j = 0; j < 4; ++j) {
        __builtin_amdgcn_wave_barrier();
        if ((lane >> 4) == j && inR) {
            int r = lane & 15;
            #pragma unroll
            for (int c = 0; c < CO; ++c) lds[wave][r][c] = s[c];
        }
        __builtin_amdgcn_wave_barrier();
        // chunk output region: rows [waveBase + 16j, +16) -> 768 floats contiguous
        size_t chunkBase = ((size_t)waveBase + (size_t)j * 16) * CO;
        #pragma unroll
        for (int i = 0; i < 3; ++i) {
            int g = i * 64 + lane;            // float4 index within chunk, 0..191
            int row = g / 12;                 // 16 rows * 12 float4s each
            int c4 = (g - row * 12) * 4;
            floatx4 val;
            val.x = lds[wave][row][c4 + 0];
            val.y = lds[wave][row][c4 + 1];
            val.z = lds[wave][row][c4 + 2];
            val.w = lds[wave][row][c4 + 3];
            size_t idx = chunkBase + (size_t)g * 4;
            if (idx < total) {
                // non-temporal: keep the 202 MB write stream from evicting rgb in L2
                __builtin_nontemporal_store(val, (floatx4*)(out + idx));
            }
        }
        __builtin_amdgcn_wave_barrier();
    }
}

extern "C" void kernel_launch(void* const* d_in, const int* in_sizes, int n_in,
                              void* d_out, int out_size, void* d_ws, size_t ws_size,
                              hipStream_t stream) {
    const float* vfeat  = (const float*)d_in[0];
    const float* rgb    = (const float*)d_in[1];
    const float* P2     = (const float*)d_in[2];
    const float* Trv2c  = (const float*)d_in[3];
    const float* rect   = (const float*)d_in[4];
    const float* prd    = (const float*)d_in[5];
    const int* vcoords  = (const int*)d_in[6];
    const int* dummy    = (const int*)d_in[7];
    float* out = (float*)d_out;

    int B = in_sizes[7];
    int N = in_sizes[6] / 4;
    float* mats = (float*)d_ws;   // B * 32 floats

    prep_kernel<<<1, 64, 0, stream>>>(P2, Trv2c, rect, prd, dummy, mats, B);

    int M = N * K3;
    int blocks = (M + BLOCK - 1) / BLOCK;
    fuse_kernel<<<blocks, BLOCK, 0, stream>>>(vfeat, rgb, mats, vcoords, out, N);
}